// Round 1
// baseline (210.590 us; speedup 1.0000x reference)
//
#include <hip/hip_runtime.h>

// FNO spectral convolution, truncated separable DFT formulation.
// B=8, H=W=256, C_IN=C_OUT=64, modes 32 x 17 (rows fftshift-centered: k_m = m-16).
//
// ws layout (floats):
//   twA [256 w][17 n][2]  : 8704          (cos,sin of 2*pi*n*w/256)
//   twB [256 h][32 m][2]  : 16384         (cos,sin of 2*pi*(m-16)*h/256, phase-reduced)
//   G   [B][H][17][64][2] : 4456448       (W-direction DFT of x)
//   T   [B][H][17][64][2] : 4456448       (after mode mix + inverse H-DFT)
// total 8,937,984 floats = 35.8 MB

#define NB 8
#define NH 256
#define NW 256
#define NC 64
#define NM1 32
#define NM2 17

__global__ void k0_tw(float* __restrict__ twA, float* __restrict__ twB) {
    const float STEP = 0.02454369260617026f; // 2*pi/256
    int t = blockIdx.x * 256 + threadIdx.x;
    if (t < 256 * 17) {
        int w = t / 17, n = t % 17;
        int ph = (n * w) & 255;
        float ang = (float)ph * STEP;
        twA[t * 2 + 0] = cosf(ang);
        twA[t * 2 + 1] = sinf(ang);
    }
    if (t < 256 * 32) {
        int h = t >> 5, m = t & 31;
        int ph = ((m - 16) * h) & 255; // two's complement & 255 == mod 256
        float ang = (float)ph * STEP;
        twB[t * 2 + 0] = cosf(ang);
        twB[t * 2 + 1] = sinf(ang);
    }
}

// K1: per (b,h): G[n][i] = sum_w x[b,h,w,i] * e^{-2pi i n w / 256}
// block = 256 threads: lane i (64) x w-quarter wq (4); partial sums reduced via LDS.
__global__ __launch_bounds__(256) void k1_fwdW(const float* __restrict__ x,
                                               const float* __restrict__ twA,
                                               float* __restrict__ G) {
    __shared__ float lds[256 * 64]; // x staged [w][i]; reused for reduction
    const int bh = blockIdx.x;
    const int tid = threadIdx.x;

    // stage x[b,h,:,:] (16384 floats) coalesced
    const float4* xg = (const float4*)(x + (size_t)bh * (NW * NC));
    #pragma unroll
    for (int k = 0; k < 16; ++k) {
        int v = k * 256 + tid;          // float4 index
        float4 val = xg[v];
        *(float4*)&lds[v * 4] = val;    // lds[w*64 + i]
    }
    __syncthreads();

    const int i = tid & 63;
    const int wq = tid >> 6;
    const int wq_u = __builtin_amdgcn_readfirstlane(wq);

    float ar[17], ai[17];
    #pragma unroll
    for (int n = 0; n < 17; ++n) { ar[n] = 0.f; ai[n] = 0.f; }

    #pragma unroll 2
    for (int ww = 0; ww < 64; ++ww) {
        float xv = lds[(wq * 64 + ww) * 64 + i];
        const float* tw = twA + (size_t)(wq_u * 64 + ww) * 34; // uniform -> s_load
        #pragma unroll
        for (int n = 0; n < 17; ++n) {
            ar[n] = fmaf(xv, tw[n * 2 + 0], ar[n]);
            ai[n] = fmaf(-xv, tw[n * 2 + 1], ai[n]); // e^{-i..}: -sin
        }
    }
    __syncthreads();

    // reduce the 4 w-quarter partials: lds as [q][i][n][2]
    #pragma unroll
    for (int n = 0; n < 17; ++n) {
        lds[((wq * 64 + i) * 17 + n) * 2 + 0] = ar[n];
        lds[((wq * 64 + i) * 17 + n) * 2 + 1] = ai[n];
    }
    __syncthreads();

    float2* G2 = (float2*)G + (size_t)bh * 17 * 64;
    for (int n = wq; n < 17; n += 4) {
        float re = 0.f, im = 0.f;
        #pragma unroll
        for (int q = 0; q < 4; ++q) {
            re += lds[((q * 64 + i) * 17 + n) * 2 + 0];
            im += lds[((q * 64 + i) * 17 + n) * 2 + 1];
        }
        G2[n * 64 + i] = make_float2(re, im);
    }
}

// K2: per (b,n) block (136 blocks, 512 threads):
//  B: xs[m][i] = sum_h G[b,h,n,i] * e^{-2pi i (m-16) h/256}
//  C: Z[m][o]  = scale * sum_i xs[m][i] * (Wr + i Wi)[m,n,i,o],  scale=(n==0?1:2)/65536
//  D: T[b,h,n,o] = sum_m Z[m][o] * e^{+2pi i (m-16) h/256}
__global__ __launch_bounds__(512) void k2_mix(const float* __restrict__ G,
                                              const float* __restrict__ Wr,
                                              const float* __restrict__ Wi,
                                              const float* __restrict__ twB,
                                              float* __restrict__ T) {
    __shared__ float2 xs2[32 * 64]; // [m][i]
    __shared__ float2 Z2[32 * 64];  // [m][o]
    const int bn = blockIdx.x;
    const int b = bn / 17, n = bn % 17;
    const int t = threadIdx.x;
    const int lane = t & 63;
    const int q = t >> 6; // 0..7
    const int q_u = __builtin_amdgcn_readfirstlane(q);

    // ---- Phase B ----
    {
        float ar[4] = {0, 0, 0, 0}, ai[4] = {0, 0, 0, 0};
        const float2* Gb = (const float2*)G + ((size_t)b * 256 * 17 + n) * 64;
        for (int h = 0; h < 256; ++h) {
            float2 g = Gb[(size_t)h * 17 * 64 + lane];
            const float* tw = twB + (size_t)(h * 32 + q_u * 4) * 2; // uniform
            #pragma unroll
            for (int j = 0; j < 4; ++j) {
                float c = tw[j * 2 + 0], s = tw[j * 2 + 1];
                ar[j] = fmaf(g.x, c, fmaf(g.y, s, ar[j]));
                ai[j] = fmaf(g.y, c, fmaf(-g.x, s, ai[j]));
            }
        }
        #pragma unroll
        for (int j = 0; j < 4; ++j)
            xs2[(q * 4 + j) * 64 + lane] = make_float2(ar[j], ai[j]);
    }
    __syncthreads();

    // ---- Phase C ----
    {
        const float scale = (n == 0 ? 1.0f : 2.0f) * (1.0f / 65536.0f);
        float zr[4] = {0, 0, 0, 0}, zi[4] = {0, 0, 0, 0};
        for (int i = 0; i < 64; ++i) {
            #pragma unroll
            for (int j = 0; j < 4; ++j) {
                int m = q * 4 + j;
                float2 xv = xs2[m * 64 + i]; // broadcast
                size_t widx = (((size_t)m * 17 + n) * 64 + i) * 64 + lane;
                float wr = Wr[widx], wi = Wi[widx];
                zr[j] = fmaf(xv.x, wr, fmaf(-xv.y, wi, zr[j]));
                zi[j] = fmaf(xv.x, wi, fmaf(xv.y, wr, zi[j]));
            }
        }
        #pragma unroll
        for (int j = 0; j < 4; ++j)
            Z2[(q * 4 + j) * 64 + lane] = make_float2(zr[j] * scale, zi[j] * scale);
    }
    __syncthreads();

    // ---- Phase D ----
    {
        float2* T2 = (float2*)T + ((size_t)b * 256 * 17 + n) * 64;
        for (int hh = 0; hh < 32; ++hh) {
            int h = q * 32 + hh;
            const float* tw = twB + (size_t)(q_u * 32 + hh) * 64; // uniform, 32 (c,s)
            float re0 = 0.f, im0 = 0.f, re1 = 0.f, im1 = 0.f;
            #pragma unroll
            for (int m = 0; m < 32; m += 2) {
                float2 z0 = Z2[m * 64 + lane];
                float c0 = tw[m * 2 + 0], s0 = tw[m * 2 + 1];
                re0 = fmaf(z0.x, c0, fmaf(-z0.y, s0, re0));
                im0 = fmaf(z0.x, s0, fmaf(z0.y, c0, im0));
                float2 z1 = Z2[(m + 1) * 64 + lane];
                float c1 = tw[m * 2 + 2], s1 = tw[m * 2 + 3];
                re1 = fmaf(z1.x, c1, fmaf(-z1.y, s1, re1));
                im1 = fmaf(z1.x, s1, fmaf(z1.y, c1, im1));
            }
            T2[(size_t)h * 17 * 64 + lane] = make_float2(re0 + re1, im0 + im1);
        }
    }
}

// K3: per (b,h): y[b,h,w,o] = sum_n c_n * Re( T[b,h,n,o] * e^{+2pi i n w/256} )
// c_n folded into Z already. 256 threads: lane o (64) x w-quarter (4).
__global__ __launch_bounds__(256) void k3_invW(const float* __restrict__ T,
                                               const float* __restrict__ twA,
                                               float* __restrict__ y) {
    const int bh = blockIdx.x;
    const int tid = threadIdx.x;
    const int o = tid & 63;
    const int wq = tid >> 6;
    const int wq_u = __builtin_amdgcn_readfirstlane(wq);

    const float2* T2 = (const float2*)T + (size_t)bh * 17 * 64;
    float tr[17], ti[17];
    #pragma unroll
    for (int n = 0; n < 17; ++n) {
        float2 v = T2[n * 64 + o];
        tr[n] = v.x;
        ti[n] = v.y;
    }

    float* yb = y + (size_t)bh * (NW * NC);
    #pragma unroll 2
    for (int ww = 0; ww < 64; ++ww) {
        int w = wq * 64 + ww;
        const float* tw = twA + (size_t)(wq_u * 64 + ww) * 34; // uniform -> s_load
        float a0 = 0.f, a1 = 0.f, a2 = 0.f, a3 = 0.f;
        #pragma unroll
        for (int n = 0; n < 16; n += 4) {
            a0 = fmaf(tr[n + 0], tw[n * 2 + 0], a0);
            a0 = fmaf(-ti[n + 0], tw[n * 2 + 1], a0);
            a1 = fmaf(tr[n + 1], tw[n * 2 + 2], a1);
            a1 = fmaf(-ti[n + 1], tw[n * 2 + 3], a1);
            a2 = fmaf(tr[n + 2], tw[n * 2 + 4], a2);
            a2 = fmaf(-ti[n + 2], tw[n * 2 + 5], a2);
            a3 = fmaf(tr[n + 3], tw[n * 2 + 6], a3);
            a3 = fmaf(-ti[n + 3], tw[n * 2 + 7], a3);
        }
        a0 = fmaf(tr[16], tw[32], a0);
        a0 = fmaf(-ti[16], tw[33], a0);
        yb[(size_t)w * 64 + o] = (a0 + a1) + (a2 + a3);
    }
}

extern "C" void kernel_launch(void* const* d_in, const int* in_sizes, int n_in,
                              void* d_out, int out_size, void* d_ws, size_t ws_size,
                              hipStream_t stream) {
    (void)in_sizes; (void)n_in; (void)out_size; (void)ws_size;
    const float* x  = (const float*)d_in[0];
    const float* Wr = (const float*)d_in[1];
    const float* Wi = (const float*)d_in[2];
    float* out = (float*)d_out;
    float* ws  = (float*)d_ws;

    float* twA = ws;                 // 8704 floats
    float* twB = ws + 8704;          // 16384 floats
    float* G   = ws + 25088;         // 4456448 floats
    float* T   = G + 4456448;        // 4456448 floats

    k0_tw<<<32, 256, 0, stream>>>(twA, twB);
    k1_fwdW<<<NB * NH, 256, 0, stream>>>(x, twA, G);
    k2_mix<<<NB * NM2, 512, 0, stream>>>(G, Wr, Wi, twB, T);
    k3_invW<<<NB * NH, 256, 0, stream>>>(T, twA, out);
}

// Round 2
// 209.378 us; speedup vs baseline: 1.0058x; 1.0058x over previous
//
#include <hip/hip_runtime.h>

// FNO spectral convolution, truncated separable DFT formulation.
// B=8, H=W=256, C_IN=C_OUT=64, modes 32 x 17 (rows fftshift-centered: k_m = m-16).
//
// ws layout (floats):
//   twA [256 w][17 n][2]  : 8704          (cos,sin of 2*pi*n*w/256)
//   twB [256 h][32 m][2]  : 16384         (cos,sin of 2*pi*(m-16)*h/256, phase-reduced)
//   G   [B][H][17][64][2] : 4456448       (W-direction DFT of x)
//   T   [B][H][17][64][2] : 4456448       (after mode mix + inverse H-DFT)
// total 8,937,984 floats = 35.8 MB

#define NB 8
#define NH 256
#define NW 256
#define NC 64
#define NM1 32
#define NM2 17

__global__ void k0_tw(float* __restrict__ twA, float* __restrict__ twB) {
    const float STEP = 0.02454369260617026f; // 2*pi/256
    int t = blockIdx.x * 256 + threadIdx.x;
    if (t < 256 * 17) {
        int w = t / 17, n = t % 17;
        int ph = (n * w) & 255;
        float ang = (float)ph * STEP;
        twA[t * 2 + 0] = cosf(ang);
        twA[t * 2 + 1] = sinf(ang);
    }
    if (t < 256 * 32) {
        int h = t >> 5, m = t & 31;
        int ph = ((m - 16) * h) & 255; // two's complement & 255 == mod 256
        float ang = (float)ph * STEP;
        twB[t * 2 + 0] = cosf(ang);
        twB[t * 2 + 1] = sinf(ang);
    }
}

// K1: per (b,h): G[n][i] = sum_w x[b,h,w,i] * e^{-2pi i n w / 256}
// block = 256 threads: lane i (64) x w-quarter wq (4); partial sums reduced via LDS.
__global__ __launch_bounds__(256) void k1_fwdW(const float* __restrict__ x,
                                               const float* __restrict__ twA,
                                               float* __restrict__ G) {
    __shared__ float lds[256 * 64]; // x staged [w][i]; reused for reduction
    const int bh = blockIdx.x;
    const int tid = threadIdx.x;

    // stage x[b,h,:,:] (16384 floats) coalesced
    const float4* xg = (const float4*)(x + (size_t)bh * (NW * NC));
    #pragma unroll
    for (int k = 0; k < 16; ++k) {
        int v = k * 256 + tid;          // float4 index
        float4 val = xg[v];
        *(float4*)&lds[v * 4] = val;    // lds[w*64 + i]
    }
    __syncthreads();

    const int i = tid & 63;
    const int wq = tid >> 6;
    const int wq_u = __builtin_amdgcn_readfirstlane(wq);

    float ar[17], ai[17];
    #pragma unroll
    for (int n = 0; n < 17; ++n) { ar[n] = 0.f; ai[n] = 0.f; }

    #pragma unroll 2
    for (int ww = 0; ww < 64; ++ww) {
        float xv = lds[(wq * 64 + ww) * 64 + i];
        const float* tw = twA + (size_t)(wq_u * 64 + ww) * 34; // uniform -> s_load
        #pragma unroll
        for (int n = 0; n < 17; ++n) {
            ar[n] = fmaf(xv, tw[n * 2 + 0], ar[n]);
            ai[n] = fmaf(-xv, tw[n * 2 + 1], ai[n]); // e^{-i..}: -sin
        }
    }
    __syncthreads();

    // reduce the 4 w-quarter partials: lds as [q][i][n][2]
    #pragma unroll
    for (int n = 0; n < 17; ++n) {
        lds[((wq * 64 + i) * 17 + n) * 2 + 0] = ar[n];
        lds[((wq * 64 + i) * 17 + n) * 2 + 1] = ai[n];
    }
    __syncthreads();

    float2* G2 = (float2*)G + (size_t)bh * 17 * 64;
    for (int n = wq; n < 17; n += 4) {
        float re = 0.f, im = 0.f;
        #pragma unroll
        for (int q = 0; q < 4; ++q) {
            re += lds[((q * 64 + i) * 17 + n) * 2 + 0];
            im += lds[((q * 64 + i) * 17 + n) * 2 + 1];
        }
        G2[n * 64 + i] = make_float2(re, im);
    }
}

// K2: per (b,n) block (136 blocks, 512 threads):
//  B: xs[m][i] = sum_h G[b,h,n,i] * e^{-2pi i (m-16) h/256}
//  C: Z[m][o]  = scale * sum_i xs[m][i] * (Wr + i Wi)[m,n,i,o],  scale=(n==0?1:2)/65536
//  D: T[b,h,n,o] = sum_m Z[m][o] * e^{+2pi i (m-16) h/256}
__global__ __launch_bounds__(512) void k2_mix(const float* __restrict__ G,
                                              const float* __restrict__ Wr,
                                              const float* __restrict__ Wi,
                                              const float* __restrict__ twB,
                                              float* __restrict__ T) {
    __shared__ float2 xs2[32 * 64]; // [m][i]
    __shared__ float2 Z2[32 * 64];  // [m][o]
    const int bn = blockIdx.x;
    const int b = bn / 17, n = bn % 17;
    const int t = threadIdx.x;
    const int lane = t & 63;
    const int q = t >> 6; // 0..7
    const int q_u = __builtin_amdgcn_readfirstlane(q);

    // ---- Phase B ----
    {
        float ar[4] = {0, 0, 0, 0}, ai[4] = {0, 0, 0, 0};
        const float2* Gb = (const float2*)G + ((size_t)b * 256 * 17 + n) * 64;
        for (int h = 0; h < 256; ++h) {
            float2 g = Gb[(size_t)h * 17 * 64 + lane];
            const float* tw = twB + (size_t)(h * 32 + q_u * 4) * 2; // uniform
            #pragma unroll
            for (int j = 0; j < 4; ++j) {
                float c = tw[j * 2 + 0], s = tw[j * 2 + 1];
                ar[j] = fmaf(g.x, c, fmaf(g.y, s, ar[j]));
                ai[j] = fmaf(g.y, c, fmaf(-g.x, s, ai[j]));
            }
        }
        #pragma unroll
        for (int j = 0; j < 4; ++j)
            xs2[(q * 4 + j) * 64 + lane] = make_float2(ar[j], ai[j]);
    }
    __syncthreads();

    // ---- Phase C ----
    {
        const float scale = (n == 0 ? 1.0f : 2.0f) * (1.0f / 65536.0f);
        float zr[4] = {0, 0, 0, 0}, zi[4] = {0, 0, 0, 0};
        for (int i = 0; i < 64; ++i) {
            #pragma unroll
            for (int j = 0; j < 4; ++j) {
                int m = q * 4 + j;
                float2 xv = xs2[m * 64 + i]; // broadcast
                size_t widx = (((size_t)m * 17 + n) * 64 + i) * 64 + lane;
                float wr = Wr[widx], wi = Wi[widx];
                zr[j] = fmaf(xv.x, wr, fmaf(-xv.y, wi, zr[j]));
                zi[j] = fmaf(xv.x, wi, fmaf(xv.y, wr, zi[j]));
            }
        }
        #pragma unroll
        for (int j = 0; j < 4; ++j)
            Z2[(q * 4 + j) * 64 + lane] = make_float2(zr[j] * scale, zi[j] * scale);
    }
    __syncthreads();

    // ---- Phase D ----
    {
        float2* T2 = (float2*)T + ((size_t)b * 256 * 17 + n) * 64;
        for (int hh = 0; hh < 32; ++hh) {
            int h = q * 32 + hh;
            const float* tw = twB + (size_t)(q_u * 32 + hh) * 64; // uniform, 32 (c,s)
            float re0 = 0.f, im0 = 0.f, re1 = 0.f, im1 = 0.f;
            #pragma unroll
            for (int m = 0; m < 32; m += 2) {
                float2 z0 = Z2[m * 64 + lane];
                float c0 = tw[m * 2 + 0], s0 = tw[m * 2 + 1];
                re0 = fmaf(z0.x, c0, fmaf(-z0.y, s0, re0));
                im0 = fmaf(z0.x, s0, fmaf(z0.y, c0, im0));
                float2 z1 = Z2[(m + 1) * 64 + lane];
                float c1 = tw[m * 2 + 2], s1 = tw[m * 2 + 3];
                re1 = fmaf(z1.x, c1, fmaf(-z1.y, s1, re1));
                im1 = fmaf(z1.x, s1, fmaf(z1.y, c1, im1));
            }
            T2[(size_t)h * 17 * 64 + lane] = make_float2(re0 + re1, im0 + im1);
        }
    }
}

// K3: per (b,h): y[b,h,w,o] = sum_n c_n * Re( T[b,h,n,o] * e^{+2pi i n w/256} )
// c_n folded into Z already. 256 threads: lane o (64) x w-quarter (4).
__global__ __launch_bounds__(256) void k3_invW(const float* __restrict__ T,
                                               const float* __restrict__ twA,
                                               float* __restrict__ y) {
    const int bh = blockIdx.x;
    const int tid = threadIdx.x;
    const int o = tid & 63;
    const int wq = tid >> 6;
    const int wq_u = __builtin_amdgcn_readfirstlane(wq);

    const float2* T2 = (const float2*)T + (size_t)bh * 17 * 64;
    float tr[17], ti[17];
    #pragma unroll
    for (int n = 0; n < 17; ++n) {
        float2 v = T2[n * 64 + o];
        tr[n] = v.x;
        ti[n] = v.y;
    }

    float* yb = y + (size_t)bh * (NW * NC);
    #pragma unroll 2
    for (int ww = 0; ww < 64; ++ww) {
        int w = wq * 64 + ww;
        const float* tw = twA + (size_t)(wq_u * 64 + ww) * 34; // uniform -> s_load
        float a0 = 0.f, a1 = 0.f, a2 = 0.f, a3 = 0.f;
        #pragma unroll
        for (int n = 0; n < 16; n += 4) {
            a0 = fmaf(tr[n + 0], tw[n * 2 + 0], a0);
            a0 = fmaf(-ti[n + 0], tw[n * 2 + 1], a0);
            a1 = fmaf(tr[n + 1], tw[n * 2 + 2], a1);
            a1 = fmaf(-ti[n + 1], tw[n * 2 + 3], a1);
            a2 = fmaf(tr[n + 2], tw[n * 2 + 4], a2);
            a2 = fmaf(-ti[n + 2], tw[n * 2 + 5], a2);
            a3 = fmaf(tr[n + 3], tw[n * 2 + 6], a3);
            a3 = fmaf(-ti[n + 3], tw[n * 2 + 7], a3);
        }
        a0 = fmaf(tr[16], tw[32], a0);
        a0 = fmaf(-ti[16], tw[33], a0);
        yb[(size_t)w * 64 + o] = (a0 + a1) + (a2 + a3);
    }
}

extern "C" void kernel_launch(void* const* d_in, const int* in_sizes, int n_in,
                              void* d_out, int out_size, void* d_ws, size_t ws_size,
                              hipStream_t stream) {
    (void)in_sizes; (void)n_in; (void)out_size; (void)ws_size;
    const float* x  = (const float*)d_in[0];
    const float* Wr = (const float*)d_in[1];
    const float* Wi = (const float*)d_in[2];
    float* out = (float*)d_out;
    float* ws  = (float*)d_ws;

    float* twA = ws;                 // 8704 floats
    float* twB = ws + 8704;          // 16384 floats
    float* G   = ws + 25088;         // 4456448 floats
    float* T   = G + 4456448;        // 4456448 floats

    k0_tw<<<32, 256, 0, stream>>>(twA, twB);
    k1_fwdW<<<NB * NH, 256, 0, stream>>>(x, twA, G);
    k2_mix<<<NB * NM2, 512, 0, stream>>>(G, Wr, Wi, twB, T);
    k3_invW<<<NB * NH, 256, 0, stream>>>(T, twA, out);
}

// Round 3
// 208.494 us; speedup vs baseline: 1.0101x; 1.0042x over previous
//
#include <hip/hip_runtime.h>

// FNO spectral convolution, truncated separable DFT formulation.
// B=8, H=W=256, C_IN=C_OUT=64, modes 32 x 17 (rows fftshift-centered: k_m = m-16).
//
// ws layout (floats):
//   twA [256 w][17 n][2]  : 8704          (cos,sin of 2*pi*n*w/256)
//   twB [256 h][32 m][2]  : 16384         (cos,sin of 2*pi*(m-16)*h/256, phase-reduced)
//   G   [B][H][17][64][2] : 4456448       (W-direction DFT of x)
//   T   [B][H][17][64][2] : 4456448       (after mode mix + inverse H-DFT)
// total 8,937,984 floats = 35.8 MB

#define NB 8
#define NH 256
#define NW 256
#define NC 64
#define NM1 32
#define NM2 17

__global__ void k0_tw(float* __restrict__ twA, float* __restrict__ twB) {
    const float STEP = 0.02454369260617026f; // 2*pi/256
    int t = blockIdx.x * 256 + threadIdx.x;
    if (t < 256 * 17) {
        int w = t / 17, n = t % 17;
        int ph = (n * w) & 255;
        float ang = (float)ph * STEP;
        twA[t * 2 + 0] = cosf(ang);
        twA[t * 2 + 1] = sinf(ang);
    }
    if (t < 256 * 32) {
        int h = t >> 5, m = t & 31;
        int ph = ((m - 16) * h) & 255; // two's complement & 255 == mod 256
        float ang = (float)ph * STEP;
        twB[t * 2 + 0] = cosf(ang);
        twB[t * 2 + 1] = sinf(ang);
    }
}

// K1: per (b,h): G[n][i] = sum_w x[b,h,w,i] * e^{-2pi i n w / 256}
// block = 256 threads: lane i (64) x w-quarter wq (4); partial sums reduced via LDS.
__global__ __launch_bounds__(256) void k1_fwdW(const float* __restrict__ x,
                                               const float* __restrict__ twA,
                                               float* __restrict__ G) {
    __shared__ float lds[256 * 64]; // x staged [w][i]; reused for reduction
    const int bh = blockIdx.x;
    const int tid = threadIdx.x;

    // stage x[b,h,:,:] (16384 floats) coalesced
    const float4* xg = (const float4*)(x + (size_t)bh * (NW * NC));
    #pragma unroll
    for (int k = 0; k < 16; ++k) {
        int v = k * 256 + tid;          // float4 index
        float4 val = xg[v];
        *(float4*)&lds[v * 4] = val;    // lds[w*64 + i]
    }
    __syncthreads();

    const int i = tid & 63;
    const int wq = tid >> 6;
    const int wq_u = __builtin_amdgcn_readfirstlane(wq);

    float ar[17], ai[17];
    #pragma unroll
    for (int n = 0; n < 17; ++n) { ar[n] = 0.f; ai[n] = 0.f; }

    #pragma unroll 2
    for (int ww = 0; ww < 64; ++ww) {
        float xv = lds[(wq * 64 + ww) * 64 + i];
        const float* tw = twA + (size_t)(wq_u * 64 + ww) * 34; // uniform -> s_load
        #pragma unroll
        for (int n = 0; n < 17; ++n) {
            ar[n] = fmaf(xv, tw[n * 2 + 0], ar[n]);
            ai[n] = fmaf(-xv, tw[n * 2 + 1], ai[n]); // e^{-i..}: -sin
        }
    }
    __syncthreads();

    // reduce the 4 w-quarter partials: lds as [q][i][n][2]
    #pragma unroll
    for (int n = 0; n < 17; ++n) {
        lds[((wq * 64 + i) * 17 + n) * 2 + 0] = ar[n];
        lds[((wq * 64 + i) * 17 + n) * 2 + 1] = ai[n];
    }
    __syncthreads();

    float2* G2 = (float2*)G + (size_t)bh * 17 * 64;
    for (int n = wq; n < 17; n += 4) {
        float re = 0.f, im = 0.f;
        #pragma unroll
        for (int q = 0; q < 4; ++q) {
            re += lds[((q * 64 + i) * 17 + n) * 2 + 0];
            im += lds[((q * 64 + i) * 17 + n) * 2 + 1];
        }
        G2[n * 64 + i] = make_float2(re, im);
    }
}

// K2: per (b,n) block (136 blocks, 512 threads):
//  B: xs[m][i] = sum_h G[b,h,n,i] * e^{-2pi i (m-16) h/256}
//  C: Z[m][o]  = scale * sum_i xs[m][i] * (Wr + i Wi)[m,n,i,o],  scale=(n==0?1:2)/65536
//  D: T[b,h,n,o] = sum_m Z[m][o] * e^{+2pi i (m-16) h/256}
__global__ __launch_bounds__(512) void k2_mix(const float* __restrict__ G,
                                              const float* __restrict__ Wr,
                                              const float* __restrict__ Wi,
                                              const float* __restrict__ twB,
                                              float* __restrict__ T) {
    __shared__ float2 xs2[32 * 64]; // [m][i]
    __shared__ float2 Z2[32 * 64];  // [m][o]
    const int bn = blockIdx.x;
    const int b = bn / 17, n = bn % 17;
    const int t = threadIdx.x;
    const int lane = t & 63;
    const int q = t >> 6; // 0..7
    const int q_u = __builtin_amdgcn_readfirstlane(q);

    // ---- Phase B ----
    {
        float ar[4] = {0, 0, 0, 0}, ai[4] = {0, 0, 0, 0};
        const float2* Gb = (const float2*)G + ((size_t)b * 256 * 17 + n) * 64;
        for (int h = 0; h < 256; ++h) {
            float2 g = Gb[(size_t)h * 17 * 64 + lane];
            const float* tw = twB + (size_t)(h * 32 + q_u * 4) * 2; // uniform
            #pragma unroll
            for (int j = 0; j < 4; ++j) {
                float c = tw[j * 2 + 0], s = tw[j * 2 + 1];
                ar[j] = fmaf(g.x, c, fmaf(g.y, s, ar[j]));
                ai[j] = fmaf(g.y, c, fmaf(-g.x, s, ai[j]));
            }
        }
        #pragma unroll
        for (int j = 0; j < 4; ++j)
            xs2[(q * 4 + j) * 64 + lane] = make_float2(ar[j], ai[j]);
    }
    __syncthreads();

    // ---- Phase C ----
    {
        const float scale = (n == 0 ? 1.0f : 2.0f) * (1.0f / 65536.0f);
        float zr[4] = {0, 0, 0, 0}, zi[4] = {0, 0, 0, 0};
        for (int i = 0; i < 64; ++i) {
            #pragma unroll
            for (int j = 0; j < 4; ++j) {
                int m = q * 4 + j;
                float2 xv = xs2[m * 64 + i]; // broadcast
                size_t widx = (((size_t)m * 17 + n) * 64 + i) * 64 + lane;
                float wr = Wr[widx], wi = Wi[widx];
                zr[j] = fmaf(xv.x, wr, fmaf(-xv.y, wi, zr[j]));
                zi[j] = fmaf(xv.x, wi, fmaf(xv.y, wr, zi[j]));
            }
        }
        #pragma unroll
        for (int j = 0; j < 4; ++j)
            Z2[(q * 4 + j) * 64 + lane] = make_float2(zr[j] * scale, zi[j] * scale);
    }
    __syncthreads();

    // ---- Phase D ----
    {
        float2* T2 = (float2*)T + ((size_t)b * 256 * 17 + n) * 64;
        for (int hh = 0; hh < 32; ++hh) {
            int h = q * 32 + hh;
            const float* tw = twB + (size_t)(q_u * 32 + hh) * 64; // uniform, 32 (c,s)
            float re0 = 0.f, im0 = 0.f, re1 = 0.f, im1 = 0.f;
            #pragma unroll
            for (int m = 0; m < 32; m += 2) {
                float2 z0 = Z2[m * 64 + lane];
                float c0 = tw[m * 2 + 0], s0 = tw[m * 2 + 1];
                re0 = fmaf(z0.x, c0, fmaf(-z0.y, s0, re0));
                im0 = fmaf(z0.x, s0, fmaf(z0.y, c0, im0));
                float2 z1 = Z2[(m + 1) * 64 + lane];
                float c1 = tw[m * 2 + 2], s1 = tw[m * 2 + 3];
                re1 = fmaf(z1.x, c1, fmaf(-z1.y, s1, re1));
                im1 = fmaf(z1.x, s1, fmaf(z1.y, c1, im1));
            }
            T2[(size_t)h * 17 * 64 + lane] = make_float2(re0 + re1, im0 + im1);
        }
    }
}

// K3: per (b,h): y[b,h,w,o] = sum_n c_n * Re( T[b,h,n,o] * e^{+2pi i n w/256} )
// c_n folded into Z already. 256 threads: lane o (64) x w-quarter (4).
__global__ __launch_bounds__(256) void k3_invW(const float* __restrict__ T,
                                               const float* __restrict__ twA,
                                               float* __restrict__ y) {
    const int bh = blockIdx.x;
    const int tid = threadIdx.x;
    const int o = tid & 63;
    const int wq = tid >> 6;
    const int wq_u = __builtin_amdgcn_readfirstlane(wq);

    const float2* T2 = (const float2*)T + (size_t)bh * 17 * 64;
    float tr[17], ti[17];
    #pragma unroll
    for (int n = 0; n < 17; ++n) {
        float2 v = T2[n * 64 + o];
        tr[n] = v.x;
        ti[n] = v.y;
    }

    float* yb = y + (size_t)bh * (NW * NC);
    #pragma unroll 2
    for (int ww = 0; ww < 64; ++ww) {
        int w = wq * 64 + ww;
        const float* tw = twA + (size_t)(wq_u * 64 + ww) * 34; // uniform -> s_load
        float a0 = 0.f, a1 = 0.f, a2 = 0.f, a3 = 0.f;
        #pragma unroll
        for (int n = 0; n < 16; n += 4) {
            a0 = fmaf(tr[n + 0], tw[n * 2 + 0], a0);
            a0 = fmaf(-ti[n + 0], tw[n * 2 + 1], a0);
            a1 = fmaf(tr[n + 1], tw[n * 2 + 2], a1);
            a1 = fmaf(-ti[n + 1], tw[n * 2 + 3], a1);
            a2 = fmaf(tr[n + 2], tw[n * 2 + 4], a2);
            a2 = fmaf(-ti[n + 2], tw[n * 2 + 5], a2);
            a3 = fmaf(tr[n + 3], tw[n * 2 + 6], a3);
            a3 = fmaf(-ti[n + 3], tw[n * 2 + 7], a3);
        }
        a0 = fmaf(tr[16], tw[32], a0);
        a0 = fmaf(-ti[16], tw[33], a0);
        yb[(size_t)w * 64 + o] = (a0 + a1) + (a2 + a3);
    }
}

extern "C" void kernel_launch(void* const* d_in, const int* in_sizes, int n_in,
                              void* d_out, int out_size, void* d_ws, size_t ws_size,
                              hipStream_t stream) {
    (void)in_sizes; (void)n_in; (void)out_size; (void)ws_size;
    const float* x  = (const float*)d_in[0];
    const float* Wr = (const float*)d_in[1];
    const float* Wi = (const float*)d_in[2];
    float* out = (float*)d_out;
    float* ws  = (float*)d_ws;

    float* twA = ws;                 // 8704 floats
    float* twB = ws + 8704;          // 16384 floats
    float* G   = ws + 25088;         // 4456448 floats
    float* T   = G + 4456448;        // 4456448 floats

    k0_tw<<<32, 256, 0, stream>>>(twA, twB);
    k1_fwdW<<<NB * NH, 256, 0, stream>>>(x, twA, G);
    k2_mix<<<NB * NM2, 512, 0, stream>>>(G, Wr, Wi, twB, T);
    k3_invW<<<NB * NH, 256, 0, stream>>>(T, twA, out);
}